// Round 4
// baseline (187.860 us; speedup 1.0000x reference)
//
#include <hip/hip_runtime.h>
#include <math.h>

#define T_ 4096
#define NROWS 16384            // B*T

typedef __attribute__((ext_vector_type(8))) short short8;   // 8 bf16
typedef __attribute__((ext_vector_type(4))) short short4v;  // 4 bf16
typedef __attribute__((ext_vector_type(4))) float float4v;
typedef __attribute__((ext_vector_type(2))) unsigned uint2v;

#define MFMA(a, b, c) __builtin_amdgcn_mfma_f32_16x16x32_bf16((a), (b), (c), 0, 0, 0)

#if defined(__has_builtin)
#if __has_builtin(__builtin_amdgcn_exp2f)
#define EXP2(x) __builtin_amdgcn_exp2f(x)
#else
#define EXP2(x) exp2f(x)
#endif
#else
#define EXP2(x) exp2f(x)
#endif

#define SCALE_Q 0.18033688011112042f   // 0.125 * log2(e), folded into Q

__device__ __forceinline__ short f2bf(float f) {
    unsigned u = __builtin_bit_cast(unsigned, f);
    u += 0x7fffu + ((u >> 16) & 1u);          // RNE truncate to bf16
    return (short)(u >> 16);
}
__device__ __forceinline__ float bf2f(short s) {
    return __builtin_bit_cast(float, ((unsigned)(unsigned short)s) << 16);
}
__device__ __forceinline__ unsigned pack_bf2(float a, float b) {
    unsigned ua = __builtin_bit_cast(unsigned, a);
    unsigned ub = __builtin_bit_cast(unsigned, b);
    ua += 0x7fffu + ((ua >> 16) & 1u);
    ub += 0x7fffu + ((ub >> 16) & 1u);
    return (ua >> 16) | (ub & 0xffff0000u);
}

// ---------------------------------------------------------------------------
// Kernel 0: weights fp32 (C x 64) -> Wt2 in FRAGMENT-MAJOR layout.
// ---------------------------------------------------------------------------
__global__ void wprep_kernel(const float* __restrict__ Wq,
                             const float* __restrict__ Wk,
                             const float* __restrict__ Wv,
                             short* __restrict__ Wt2)
{
    const int ck = blockIdx.x;            // 0..31 (k chunk of 32)
    const int t = threadIdx.x;
    const int sub = t >> 6, lane = t & 63;
    const int ln = lane & 15, quad = lane >> 4;
#pragma unroll
    for (int jj = 0; jj < 3; ++jj) {
        const int nt = sub * 3 + jj;      // 0..11
        const float* W = (nt < 4) ? Wq : (nt < 8) ? Wk : Wv;
        const int col = (nt & 3) * 16 + ln;
        short8 o;
#pragma unroll
        for (int j = 0; j < 8; ++j)
            o[j] = f2bf(W[(size_t)(ck * 32 + quad * 8 + j) * 64 + col]);
        *(short8*)(Wt2 + ((size_t)(ck * 12 + nt) * 64 + lane) * 8) = o;
    }
}

// ---------------------------------------------------------------------------
// Kernel 1: MFMA QKV projection + fused RoPE, 4-way split-K, 32 rows/block.
// (unchanged this round)
// ---------------------------------------------------------------------------
__global__ __launch_bounds__(256, 2) void qkv_kernel(
    const float* __restrict__ x, const float* __restrict__ cosp,
    const float* __restrict__ sinp, const short* __restrict__ Wt2,
    short* __restrict__ Qb, short* __restrict__ Ks, short* __restrict__ Vs)
{
    __shared__ short4v MB[4][2][12][64];    // bf16 partial acc, 48 KB
    __shared__ short KT[32][72];            // K transpose tile (+pad), 4.5 KB

    const int t = threadIdx.x, w = t >> 6, lane = t & 63;
    const int ln = lane & 15, quad = lane >> 4;
    const int rb = blockIdx.x * 32;
    const int k0 = w * 256;

    const float* xp0 = x + (size_t)(rb + ln) * 1024 + k0 + quad * 8;
    const float* xp1 = x + (size_t)(rb + 16 + ln) * 1024 + k0 + quad * 8;
    const short* wp2 = Wt2 + ((size_t)(w * 8) * 12 * 64 + lane) * 8;

    // ---- Phase A: preload + convert all x for this wave ----
    short8 a[2][8];
#pragma unroll
    for (int af = 0; af < 2; ++af) {
        const float* xp = af ? xp1 : xp0;
        float4 xf[16];
#pragma unroll
        for (int it = 0; it < 8; ++it) {
            xf[it * 2]     = *(const float4*)(xp + it * 32);
            xf[it * 2 + 1] = *(const float4*)(xp + it * 32 + 4);
        }
#pragma unroll
        for (int it = 0; it < 8; ++it) {
            short8 v;
            v[0] = f2bf(xf[it * 2].x);     v[1] = f2bf(xf[it * 2].y);
            v[2] = f2bf(xf[it * 2].z);     v[3] = f2bf(xf[it * 2].w);
            v[4] = f2bf(xf[it * 2 + 1].x); v[5] = f2bf(xf[it * 2 + 1].y);
            v[6] = f2bf(xf[it * 2 + 1].z); v[7] = f2bf(xf[it * 2 + 1].w);
            a[af][it] = v;
        }
    }

    float4v acc[2][12];
#pragma unroll
    for (int af = 0; af < 2; ++af)
#pragma unroll
        for (int i = 0; i < 12; ++i) acc[af][i] = (float4v){0.f, 0.f, 0.f, 0.f};

    // ---- Phase B: W (frag-major, coalesced) -> MFMA ----
#pragma unroll
    for (int it = 0; it < 8; ++it) {
        short8 bf[12];
#pragma unroll
        for (int nt = 0; nt < 12; ++nt)
            bf[nt] = *(const short8*)(wp2 + (size_t)(it * 12 + nt) * 512);
#pragma unroll
        for (int nt = 0; nt < 12; ++nt) {
            acc[0][nt] = MFMA(a[0][it], bf[nt], acc[0][nt]);
            acc[1][nt] = MFMA(a[1][it], bf[nt], acc[1][nt]);
        }
    }

    // partials -> LDS (bf16)
#pragma unroll
    for (int af = 0; af < 2; ++af)
#pragma unroll
        for (int nt = 0; nt < 12; ++nt) {
            short4v pv;
#pragma unroll
            for (int reg = 0; reg < 4; ++reg) pv[reg] = f2bf(acc[af][nt][reg]);
            MB[w][af][nt][lane] = pv;
        }
    __syncthreads();

    // merge + epilogue: wave w handles nt = 3w..3w+2, both row groups
    const int b  = rb >> 12;
    const int kt = (rb & (T_ - 1)) >> 6;
#pragma unroll
    for (int af = 0; af < 2; ++af) {
        const int rb16 = rb + af * 16;
#pragma unroll
        for (int j = 0; j < 3; ++j) {
            const int nt = w * 3 + j;
            float m[4] = {0.f, 0.f, 0.f, 0.f};
#pragma unroll
            for (int p = 0; p < 4; ++p) {
                const short4v pv = MB[p][af][nt][lane];
#pragma unroll
                for (int reg = 0; reg < 4; ++reg) m[reg] += bf2f(pv[reg]);
            }
            if (nt < 4) {                          // Q + RoPE (scaled), row-major
                const int col = nt * 16 + ln;
#pragma unroll
                for (int reg = 0; reg < 4; ++reg) {
                    const int g  = rb16 + quad * 4 + reg;
                    const int tp = g & (T_ - 1);
                    const float cv = cosp[(size_t)tp * 64 + col];
                    const float sv = sinp[(size_t)tp * 64 + col];
                    const float v  = m[reg];
                    const float vp = __shfl_xor(v, 1, 64);
                    const float rot = (ln & 1) ? vp : -vp;
                    Qb[(size_t)g * 64 + col] = f2bf(fmaf(v, cv, rot * sv) * SCALE_Q);
                }
            } else if (nt < 8) {                   // K + RoPE -> LDS transpose tile
                const int col = (nt & 3) * 16 + ln;
#pragma unroll
                for (int reg = 0; reg < 4; ++reg) {
                    const int g  = rb16 + quad * 4 + reg;
                    const int tp = g & (T_ - 1);
                    const float cv = cosp[(size_t)tp * 64 + col];
                    const float sv = sinp[(size_t)tp * 64 + col];
                    const float v  = m[reg];
                    const float vp = __shfl_xor(v, 1, 64);
                    const float rot = (ln & 1) ? vp : -vp;
                    KT[af * 16 + quad * 4 + reg][col] = f2bf(fmaf(v, cv, rot * sv));
                }
            } else {                               // V -> swizzled B-frag layout
                const int vnt = nt - 8;
                const int rowgrp = (rb16 >> 4) & 3;
                const int hh = rowgrp >> 1;
                const int qp = (rowgrp & 1) * 2 + (quad >> 1);
                const int jb = (quad & 1) * 4;
                short4v pv;
#pragma unroll
                for (int reg = 0; reg < 4; ++reg) pv[reg] = f2bf(m[reg]);
                const size_t addr =
                    ((((size_t)(b * 64 + kt) * 4 + vnt) * 2 + hh) * 64 + qp * 16 + ln) * 8 + jb;
                *(short4v*)(Vs + addr) = pv;
            }
        }
    }
    __syncthreads();   // KT complete

    // K frag-major store: wave w handles (af2 = w>>1, h2 = w&1); coalesced 1 KB
    {
        const int af2 = w >> 1, h2 = w & 1;
        const int st2 = ((rb >> 4) & 3) + af2;     // 16-row group within 64-tile
        const short8 kfrag = *(const short8*)(&KT[af2 * 16 + ln][h2 * 32 + quad * 8]);
        *(short8*)(Ks + (((size_t)(b * 64 + kt) * 8 + st2 * 2 + h2) * 64 + lane) * 8) = kfrag;
    }
}

// ---------------------------------------------------------------------------
// Kernel 2: MFMA flash attention — ROUND 2 restructure (resubmitted after
// infra failure):
//   * Q-tile 32 rows (two 16-row groups A/B share each loaded K/V tile):
//     K/V cache traffic and tile-STEP count HALVE (532 -> 266 MB).
//   * 256 blocks x 512 threads (8 waves, 8-way split-K over kt).
//     Each block does the complementary job pair (j, 127-j): exactly 66
//     tile-steps per block -> perfect load balance. 1 block/CU, 2 waves/SIMD
//     (same occupancy as before).
//   * LDS: per-wave P tiles (8 waves x 2 groups) union-aliased with the
//     epilogue OL/SL merge buffers (phases separated by barriers). 70.6 KB.
// ---------------------------------------------------------------------------
#define LOADK(kf, ktv)                                                         \
    {   const short* _kb = Ksp + (size_t)(ktv) * 4096 + lane * 8;              \
        _Pragma("unroll")                                                      \
        for (int u = 0; u < 8; ++u) kf[u] = *(const short8*)(_kb + u * 512); }

#define LOADV(vf, ktv)                                                         \
    {   const short* _vb = Vp + (size_t)(ktv) * 4096 + lane * 8;               \
        _Pragma("unroll")                                                      \
        for (int u = 0; u < 8; ++u) vf[u] = *(const short8*)(_vb + u * 512); }

#define STEP(ktv, kf, vf, masked)                                              \
    {   float4v sA[4], sB[4];                                                  \
        _Pragma("unroll")                                                      \
        for (int st = 0; st < 4; ++st) {                                       \
            sA[st] = (float4v){0.f, 0.f, 0.f, 0.f};                            \
            sA[st] = MFMA(kf[st * 2],     qA0, sA[st]);  /* S^T = K*Q^T */     \
            sA[st] = MFMA(kf[st * 2 + 1], qA1, sA[st]);                        \
            sB[st] = (float4v){0.f, 0.f, 0.f, 0.f};                            \
            sB[st] = MFMA(kf[st * 2],     qB0, sB[st]);                        \
            sB[st] = MFMA(kf[st * 2 + 1], qB1, sB[st]);                        \
        }                                                                      \
        if (masked) {                                                          \
            _Pragma("unroll")                                                  \
            for (int st = 0; st < 4; ++st)                                     \
                _Pragma("unroll")                                              \
                for (int r = 0; r < 4; ++r) {                                  \
                    const int kc = (ktv) * 64 + st * 16 + quad * 4 + r;        \
                    if (kc > qr0 + ln)      sA[st][r] = -__builtin_inff();     \
                    if (kc > qr0 + 16 + ln) sB[st][r] = -__builtin_inff();     \
                }                                                              \
        }                                                                      \
        _Pragma("unroll")                                                      \
        for (int st = 0; st < 4; ++st)                                         \
            _Pragma("unroll")                                                  \
            for (int r = 0; r < 4; ++r) {                                      \
                const float pA = EXP2(sA[st][r]);                              \
                sA[st][r] = pA; lsumA += pA;                                   \
                const float pB = EXP2(sB[st][r]);                              \
                sB[st][r] = pB; lsumB += pB;                                   \
            }                                                                  \
        _Pragma("unroll")                                                      \
        for (int st = 0; st < 4; ++st) {                                       \
            uint2v pkA, pkB;                                                   \
            pkA[0] = pack_bf2(sA[st][0], sA[st][1]);                           \
            pkA[1] = pack_bf2(sA[st][2], sA[st][3]);                           \
            *(uint2v*)(pwA + ln * 104 + st * 16 + quad * 4) = pkA;             \
            pkB[0] = pack_bf2(sB[st][0], sB[st][1]);                           \
            pkB[1] = pack_bf2(sB[st][2], sB[st][3]);                           \
            *(uint2v*)(pwB + ln * 104 + st * 16 + quad * 4) = pkB;             \
        }                                                                      \
        const short8 aA0 = *(const short8*)(pwA + ln * 104 + quad * 8);        \
        const short8 aA1 = *(const short8*)(pwA + ln * 104 + quad * 8 + 32);   \
        const short8 aB0 = *(const short8*)(pwB + ln * 104 + quad * 8);        \
        const short8 aB1 = *(const short8*)(pwB + ln * 104 + quad * 8 + 32);   \
        _Pragma("unroll")                                                      \
        for (int vn = 0; vn < 4; ++vn) {                                       \
            oA[vn] = MFMA(aA0, vf[vn * 2],     oA[vn]);                        \
            oA[vn] = MFMA(aA1, vf[vn * 2 + 1], oA[vn]);                        \
            oB[vn] = MFMA(aB0, vf[vn * 2],     oB[vn]);                        \
            oB[vn] = MFMA(aB1, vf[vn * 2 + 1], oB[vn]);                        \
        }                                                                      \
    }

__global__ __launch_bounds__(512, 2) void attn_kernel(
    const short* __restrict__ Qb, const short* __restrict__ Ks,
    const short* __restrict__ Vs, float* __restrict__ out)
{
    // Union-aliased shared memory:
    //   main loop : PLs = short[8 waves][2 groups][16*104]   (53,248 B)
    //   epilogue  : OLf = float[8][32][68] (69,632 B) ; SLf = float[8][32]
    __shared__ __align__(16) unsigned char smem[70656];
    short* const PLs = (short*)smem;
    float* const OLf = (float*)smem;
    float* const SLf = (float*)(smem + 69632);

    const int t = threadIdx.x, w = t >> 6, lane = t & 63;
    const int ln = lane & 15, quad = lane >> 4;
    const int bid = (int)blockIdx.x;
    const int b = bid >> 6;            // batch 0..3
    const int q = bid & 63;            // pair id 0..63

    const short* Qp  = Qb + (size_t)b * T_ * 64;
    const short* Ksp = Ks + (size_t)b * T_ * 64;
    const short* Vp  = Vs + (size_t)b * T_ * 64;
    short* const pwA = PLs + (size_t)(w * 2) * 1664;
    short* const pwB = pwA + 1664;

    for (int job = 0; job < 2; ++job) {
        const int j   = job ? 127 - q : q;      // complementary pair: 66 steps/block
        const int qr0 = j * 32;

        const short8 qA0 = *(const short8*)(Qp + (size_t)(qr0 + ln) * 64 + quad * 8);
        const short8 qA1 = *(const short8*)(Qp + (size_t)(qr0 + ln) * 64 + quad * 8 + 32);
        const short8 qB0 = *(const short8*)(Qp + (size_t)(qr0 + 16 + ln) * 64 + quad * 8);
        const short8 qB1 = *(const short8*)(Qp + (size_t)(qr0 + 16 + ln) * 64 + quad * 8 + 32);

        float lsumA = 0.f, lsumB = 0.f;
        float4v oA[4], oB[4];
#pragma unroll
        for (int i = 0; i < 4; ++i) {
            oA[i] = (float4v){0.f, 0.f, 0.f, 0.f};
            oB[i] = (float4v){0.f, 0.f, 0.f, 0.f};
        }

        const int ktend = j >> 1;               // = (32j+31)>>6
        short8 k0f[8], k1f[8], v0f[8], v1f[8];

        int kt = w;
        if (kt <= ktend) {
            LOADK(k0f, kt)
            LOADV(v0f, kt)
            while (true) {
                {
                    const bool more = (kt + 8) <= ktend;
                    if (more) { LOADK(k1f, kt + 8) LOADV(v1f, kt + 8) }
                    STEP(kt, k0f, v0f, kt == ktend)
                    kt += 8;
                    if (!more) break;
                }
                {
                    const bool more = (kt + 8) <= ktend;
                    if (more) { LOADK(k0f, kt + 8) LOADV(v0f, kt + 8) }
                    STEP(kt, k1f, v1f, kt == ktend)
                    kt += 8;
                    if (!more) break;
                }
            }
        }

        // deferred l reduction over quad (2 shfls per group)
        lsumA += __shfl_xor(lsumA, 16, 64);
        lsumA += __shfl_xor(lsumA, 32, 64);
        lsumB += __shfl_xor(lsumB, 16, 64);
        lsumB += __shfl_xor(lsumB, 32, 64);

        __syncthreads();   // all waves done with PLs before OL overwrites it

        // partials -> LDS (plain sum merge; no rescale needed)
#pragma unroll
        for (int vn = 0; vn < 4; ++vn)
#pragma unroll
            for (int r = 0; r < 4; ++r) {
                OLf[((size_t)w * 32 + quad * 4 + r) * 68 + vn * 16 + ln]      = oA[vn][r];
                OLf[((size_t)w * 32 + 16 + quad * 4 + r) * 68 + vn * 16 + ln] = oB[vn][r];
            }
        if (quad == 0) {
            SLf[w * 32 + ln]      = lsumA;
            SLf[w * 32 + 16 + ln] = lsumB;
        }
        __syncthreads();

        // merge: (w,quad) owns one of 32 rows; sum 8 split-K partials
        const int row = w * 4 + quad;
        float lstar = 0.f;
#pragma unroll
        for (int p = 0; p < 8; ++p) lstar += SLf[p * 32 + row];
        float ox = 0.f, oy = 0.f, oz = 0.f, ow_ = 0.f;
#pragma unroll
        for (int p = 0; p < 8; ++p) {
            const float4 ov = *(const float4*)&OLf[((size_t)p * 32 + row) * 68 + ln * 4];
            ox += ov.x; oy += ov.y; oz += ov.z; ow_ += ov.w;
        }
        const float inv = 1.f / lstar;
        float4 res; res.x = ox * inv; res.y = oy * inv; res.z = oz * inv; res.w = ow_ * inv;
        *(float4*)(out + ((size_t)b * T_ + qr0 + row) * 64 + ln * 4) = res;
        __syncthreads();   // LDS reused by next job
    }
}

extern "C" void kernel_launch(void* const* d_in, const int* in_sizes, int n_in,
                              void* d_out, int out_size, void* d_ws, size_t ws_size,
                              hipStream_t stream)
{
    const float* x    = (const float*)d_in[0];
    const float* cosp = (const float*)d_in[1];
    const float* sinp = (const float*)d_in[2];
    // d_in[3] = tril: unused (causality structural)
    const float* Wq   = (const float*)d_in[4];
    const float* Wk   = (const float*)d_in[5];
    const float* Wv   = (const float*)d_in[6];
    float* out = (float*)d_out;

    short* Qb  = (short*)d_ws;                // 16384*64 bf16 (pre-scaled)
    short* Ks  = Qb + (size_t)NROWS * 64;     // A-frag-major K
    short* Vs  = Ks + (size_t)NROWS * 64;     // B-frag-major V
    short* Wt2 = Vs + (size_t)NROWS * 64;     // 32*12*64*8 bf16 (frag-major)

    wprep_kernel<<<32, 256, 0, stream>>>(Wq, Wk, Wv, Wt2);
    qkv_kernel<<<NROWS / 32, 256, 0, stream>>>(x, cosp, sinp, Wt2, Qb, Ks, Vs);
    attn_kernel<<<256, 512, 0, stream>>>(Qb, Ks, Vs, out);
}

// Round 6
// 175.508 us; speedup vs baseline: 1.0704x; 1.0704x over previous
//
#include <hip/hip_runtime.h>
#include <math.h>

#define T_ 4096
#define NROWS 16384            // B*T

typedef __attribute__((ext_vector_type(8))) short short8;   // 8 bf16
typedef __attribute__((ext_vector_type(4))) short short4v;  // 4 bf16
typedef __attribute__((ext_vector_type(4))) float float4v;
typedef __attribute__((ext_vector_type(2))) unsigned uint2v;

#define MFMA(a, b, c) __builtin_amdgcn_mfma_f32_16x16x32_bf16((a), (b), (c), 0, 0, 0)

#if defined(__has_builtin)
#if __has_builtin(__builtin_amdgcn_exp2f)
#define EXP2(x) __builtin_amdgcn_exp2f(x)
#else
#define EXP2(x) exp2f(x)
#endif
#else
#define EXP2(x) exp2f(x)
#endif

#define SCALE_Q 0.18033688011112042f   // 0.125 * log2(e), folded into Q

__device__ __forceinline__ short f2bf(float f) {
    unsigned u = __builtin_bit_cast(unsigned, f);
    u += 0x7fffu + ((u >> 16) & 1u);          // RNE truncate to bf16
    return (short)(u >> 16);
}
__device__ __forceinline__ float bf2f(short s) {
    return __builtin_bit_cast(float, ((unsigned)(unsigned short)s) << 16);
}
__device__ __forceinline__ unsigned pack_bf2(float a, float b) {
    unsigned ua = __builtin_bit_cast(unsigned, a);
    unsigned ub = __builtin_bit_cast(unsigned, b);
    ua += 0x7fffu + ((ua >> 16) & 1u);
    ub += 0x7fffu + ((ub >> 16) & 1u);
    return (ua >> 16) | (ub & 0xffff0000u);
}

// ---------------------------------------------------------------------------
// Kernel 0: weights fp32 (C x 64) -> Wt2 in FRAGMENT-MAJOR layout.
// ---------------------------------------------------------------------------
__global__ void wprep_kernel(const float* __restrict__ Wq,
                             const float* __restrict__ Wk,
                             const float* __restrict__ Wv,
                             short* __restrict__ Wt2)
{
    const int ck = blockIdx.x;            // 0..31 (k chunk of 32)
    const int t = threadIdx.x;
    const int sub = t >> 6, lane = t & 63;
    const int ln = lane & 15, quad = lane >> 4;
#pragma unroll
    for (int jj = 0; jj < 3; ++jj) {
        const int nt = sub * 3 + jj;      // 0..11
        const float* W = (nt < 4) ? Wq : (nt < 8) ? Wk : Wv;
        const int col = (nt & 3) * 16 + ln;
        short8 o;
#pragma unroll
        for (int j = 0; j < 8; ++j)
            o[j] = f2bf(W[(size_t)(ck * 32 + quad * 8 + j) * 64 + col]);
        *(short8*)(Wt2 + ((size_t)(ck * 12 + nt) * 64 + lane) * 8) = o;
    }
}

// ---------------------------------------------------------------------------
// Kernel 1: MFMA QKV projection + fused RoPE, 4-way split-K, 32 rows/block.
// (unchanged this round)
// ---------------------------------------------------------------------------
__global__ __launch_bounds__(256, 2) void qkv_kernel(
    const float* __restrict__ x, const float* __restrict__ cosp,
    const float* __restrict__ sinp, const short* __restrict__ Wt2,
    short* __restrict__ Qb, short* __restrict__ Ks, short* __restrict__ Vs)
{
    __shared__ short4v MB[4][2][12][64];    // bf16 partial acc, 48 KB
    __shared__ short KT[32][72];            // K transpose tile (+pad), 4.5 KB

    const int t = threadIdx.x, w = t >> 6, lane = t & 63;
    const int ln = lane & 15, quad = lane >> 4;
    const int rb = blockIdx.x * 32;
    const int k0 = w * 256;

    const float* xp0 = x + (size_t)(rb + ln) * 1024 + k0 + quad * 8;
    const float* xp1 = x + (size_t)(rb + 16 + ln) * 1024 + k0 + quad * 8;
    const short* wp2 = Wt2 + ((size_t)(w * 8) * 12 * 64 + lane) * 8;

    // ---- Phase A: preload + convert all x for this wave ----
    short8 a[2][8];
#pragma unroll
    for (int af = 0; af < 2; ++af) {
        const float* xp = af ? xp1 : xp0;
        float4 xf[16];
#pragma unroll
        for (int it = 0; it < 8; ++it) {
            xf[it * 2]     = *(const float4*)(xp + it * 32);
            xf[it * 2 + 1] = *(const float4*)(xp + it * 32 + 4);
        }
#pragma unroll
        for (int it = 0; it < 8; ++it) {
            short8 v;
            v[0] = f2bf(xf[it * 2].x);     v[1] = f2bf(xf[it * 2].y);
            v[2] = f2bf(xf[it * 2].z);     v[3] = f2bf(xf[it * 2].w);
            v[4] = f2bf(xf[it * 2 + 1].x); v[5] = f2bf(xf[it * 2 + 1].y);
            v[6] = f2bf(xf[it * 2 + 1].z); v[7] = f2bf(xf[it * 2 + 1].w);
            a[af][it] = v;
        }
    }

    float4v acc[2][12];
#pragma unroll
    for (int af = 0; af < 2; ++af)
#pragma unroll
        for (int i = 0; i < 12; ++i) acc[af][i] = (float4v){0.f, 0.f, 0.f, 0.f};

    // ---- Phase B: W (frag-major, coalesced) -> MFMA ----
#pragma unroll
    for (int it = 0; it < 8; ++it) {
        short8 bf[12];
#pragma unroll
        for (int nt = 0; nt < 12; ++nt)
            bf[nt] = *(const short8*)(wp2 + (size_t)(it * 12 + nt) * 512);
#pragma unroll
        for (int nt = 0; nt < 12; ++nt) {
            acc[0][nt] = MFMA(a[0][it], bf[nt], acc[0][nt]);
            acc[1][nt] = MFMA(a[1][it], bf[nt], acc[1][nt]);
        }
    }

    // partials -> LDS (bf16)
#pragma unroll
    for (int af = 0; af < 2; ++af)
#pragma unroll
        for (int nt = 0; nt < 12; ++nt) {
            short4v pv;
#pragma unroll
            for (int reg = 0; reg < 4; ++reg) pv[reg] = f2bf(acc[af][nt][reg]);
            MB[w][af][nt][lane] = pv;
        }
    __syncthreads();

    // merge + epilogue: wave w handles nt = 3w..3w+2, both row groups
    const int b  = rb >> 12;
    const int kt = (rb & (T_ - 1)) >> 6;
#pragma unroll
    for (int af = 0; af < 2; ++af) {
        const int rb16 = rb + af * 16;
#pragma unroll
        for (int j = 0; j < 3; ++j) {
            const int nt = w * 3 + j;
            float m[4] = {0.f, 0.f, 0.f, 0.f};
#pragma unroll
            for (int p = 0; p < 4; ++p) {
                const short4v pv = MB[p][af][nt][lane];
#pragma unroll
                for (int reg = 0; reg < 4; ++reg) m[reg] += bf2f(pv[reg]);
            }
            if (nt < 4) {                          // Q + RoPE (scaled), row-major
                const int col = nt * 16 + ln;
#pragma unroll
                for (int reg = 0; reg < 4; ++reg) {
                    const int g  = rb16 + quad * 4 + reg;
                    const int tp = g & (T_ - 1);
                    const float cv = cosp[(size_t)tp * 64 + col];
                    const float sv = sinp[(size_t)tp * 64 + col];
                    const float v  = m[reg];
                    const float vp = __shfl_xor(v, 1, 64);
                    const float rot = (ln & 1) ? vp : -vp;
                    Qb[(size_t)g * 64 + col] = f2bf(fmaf(v, cv, rot * sv) * SCALE_Q);
                }
            } else if (nt < 8) {                   // K + RoPE -> LDS transpose tile
                const int col = (nt & 3) * 16 + ln;
#pragma unroll
                for (int reg = 0; reg < 4; ++reg) {
                    const int g  = rb16 + quad * 4 + reg;
                    const int tp = g & (T_ - 1);
                    const float cv = cosp[(size_t)tp * 64 + col];
                    const float sv = sinp[(size_t)tp * 64 + col];
                    const float v  = m[reg];
                    const float vp = __shfl_xor(v, 1, 64);
                    const float rot = (ln & 1) ? vp : -vp;
                    KT[af * 16 + quad * 4 + reg][col] = f2bf(fmaf(v, cv, rot * sv));
                }
            } else {                               // V -> swizzled B-frag layout
                const int vnt = nt - 8;
                const int rowgrp = (rb16 >> 4) & 3;
                const int hh = rowgrp >> 1;
                const int qp = (rowgrp & 1) * 2 + (quad >> 1);
                const int jb = (quad & 1) * 4;
                short4v pv;
#pragma unroll
                for (int reg = 0; reg < 4; ++reg) pv[reg] = f2bf(m[reg]);
                const size_t addr =
                    ((((size_t)(b * 64 + kt) * 4 + vnt) * 2 + hh) * 64 + qp * 16 + ln) * 8 + jb;
                *(short4v*)(Vs + addr) = pv;
            }
        }
    }
    __syncthreads();   // KT complete

    // K frag-major store: wave w handles (af2 = w>>1, h2 = w&1); coalesced 1 KB
    {
        const int af2 = w >> 1, h2 = w & 1;
        const int st2 = ((rb >> 4) & 3) + af2;     // 16-row group within 64-tile
        const short8 kfrag = *(const short8*)(&KT[af2 * 16 + ln][h2 * 32 + quad * 8]);
        *(short8*)(Ks + (((size_t)(b * 64 + kt) * 8 + st2 * 2 + h2) * 64 + lane) * 8) = kfrag;
    }
}

// ---------------------------------------------------------------------------
// Kernel 2: MFMA flash attention — ROUND 4 (resubmitted after infra failure):
// keep the 32-row Q-tile / 8-wave restructure (halved K/V traffic, verified
// correct in round 2) but FIX THE REGISTER PRESSURE that made it regress:
//   * V is single-buffered (load issued before the QK MFMAs of the same
//     tile; PV uses it ~300 cycles later — latency hidden, no 2nd buffer).
//   * K keeps two alternating prefetch buffers (kfA/kfB) so the next tile's
//     QK never waits cold.
//   * Frees 32 VGPR vs round 2 (~230-250 -> ~200-215): no spill at the
//     256-VGPR cap of __launch_bounds__(512,2).
// ---------------------------------------------------------------------------
#define LOADK(kf, ktv)                                                         \
    {   const short* _kb = Ksp + (size_t)(ktv) * 4096 + lane * 8;              \
        _Pragma("unroll")                                                      \
        for (int u = 0; u < 8; ++u) kf[u] = *(const short8*)(_kb + u * 512); }

#define LOADV(vf, ktv)                                                         \
    {   const short* _vb = Vp + (size_t)(ktv) * 4096 + lane * 8;               \
        _Pragma("unroll")                                                      \
        for (int u = 0; u < 8; ++u) vf[u] = *(const short8*)(_vb + u * 512); }

#define STEP(ktv, kf, vf, masked)                                              \
    {   float4v sA[4], sB[4];                                                  \
        _Pragma("unroll")                                                      \
        for (int st = 0; st < 4; ++st) {                                       \
            sA[st] = (float4v){0.f, 0.f, 0.f, 0.f};                            \
            sA[st] = MFMA(kf[st * 2],     qA0, sA[st]);  /* S^T = K*Q^T */     \
            sA[st] = MFMA(kf[st * 2 + 1], qA1, sA[st]);                        \
            sB[st] = (float4v){0.f, 0.f, 0.f, 0.f};                            \
            sB[st] = MFMA(kf[st * 2],     qB0, sB[st]);                        \
            sB[st] = MFMA(kf[st * 2 + 1], qB1, sB[st]);                        \
        }                                                                      \
        if (masked) {                                                          \
            _Pragma("unroll")                                                  \
            for (int st = 0; st < 4; ++st)                                     \
                _Pragma("unroll")                                              \
                for (int r = 0; r < 4; ++r) {                                  \
                    const int kc = (ktv) * 64 + st * 16 + quad * 4 + r;        \
                    if (kc > qr0 + ln)      sA[st][r] = -__builtin_inff();     \
                    if (kc > qr0 + 16 + ln) sB[st][r] = -__builtin_inff();     \
                }                                                              \
        }                                                                      \
        _Pragma("unroll")                                                      \
        for (int st = 0; st < 4; ++st)                                         \
            _Pragma("unroll")                                                  \
            for (int r = 0; r < 4; ++r) {                                      \
                const float pA = EXP2(sA[st][r]);                              \
                sA[st][r] = pA; lsumA += pA;                                   \
                const float pB = EXP2(sB[st][r]);                              \
                sB[st][r] = pB; lsumB += pB;                                   \
            }                                                                  \
        _Pragma("unroll")                                                      \
        for (int st = 0; st < 4; ++st) {                                       \
            uint2v pkA, pkB;                                                   \
            pkA[0] = pack_bf2(sA[st][0], sA[st][1]);                           \
            pkA[1] = pack_bf2(sA[st][2], sA[st][3]);                           \
            *(uint2v*)(pwA + ln * 104 + st * 16 + quad * 4) = pkA;             \
            pkB[0] = pack_bf2(sB[st][0], sB[st][1]);                           \
            pkB[1] = pack_bf2(sB[st][2], sB[st][3]);                           \
            *(uint2v*)(pwB + ln * 104 + st * 16 + quad * 4) = pkB;             \
        }                                                                      \
        const short8 aA0 = *(const short8*)(pwA + ln * 104 + quad * 8);        \
        const short8 aA1 = *(const short8*)(pwA + ln * 104 + quad * 8 + 32);   \
        const short8 aB0 = *(const short8*)(pwB + ln * 104 + quad * 8);        \
        const short8 aB1 = *(const short8*)(pwB + ln * 104 + quad * 8 + 32);   \
        _Pragma("unroll")                                                      \
        for (int vn = 0; vn < 4; ++vn) {                                       \
            oA[vn] = MFMA(aA0, vf[vn * 2],     oA[vn]);                        \
            oA[vn] = MFMA(aA1, vf[vn * 2 + 1], oA[vn]);                        \
            oB[vn] = MFMA(aB0, vf[vn * 2],     oB[vn]);                        \
            oB[vn] = MFMA(aB1, vf[vn * 2 + 1], oB[vn]);                        \
        }                                                                      \
    }

__global__ __launch_bounds__(512, 2) void attn_kernel(
    const short* __restrict__ Qb, const short* __restrict__ Ks,
    const short* __restrict__ Vs, float* __restrict__ out)
{
    // Union-aliased shared memory:
    //   main loop : PLs = short[8 waves][2 groups][16*104]   (53,248 B)
    //   epilogue  : OLf = float[8][32][68] (69,632 B) ; SLf = float[8][32]
    __shared__ __align__(16) unsigned char smem[70656];
    short* const PLs = (short*)smem;
    float* const OLf = (float*)smem;
    float* const SLf = (float*)(smem + 69632);

    const int t = threadIdx.x, w = t >> 6, lane = t & 63;
    const int ln = lane & 15, quad = lane >> 4;
    const int bid = (int)blockIdx.x;
    const int b = bid >> 6;            // batch 0..3
    const int q = bid & 63;            // pair id 0..63

    const short* Qp  = Qb + (size_t)b * T_ * 64;
    const short* Ksp = Ks + (size_t)b * T_ * 64;
    const short* Vp  = Vs + (size_t)b * T_ * 64;
    short* const pwA = PLs + (size_t)(w * 2) * 1664;
    short* const pwB = pwA + 1664;

    for (int job = 0; job < 2; ++job) {
        const int j   = job ? 127 - q : q;      // complementary pair: 65 steps/block
        const int qr0 = j * 32;

        const short8 qA0 = *(const short8*)(Qp + (size_t)(qr0 + ln) * 64 + quad * 8);
        const short8 qA1 = *(const short8*)(Qp + (size_t)(qr0 + ln) * 64 + quad * 8 + 32);
        const short8 qB0 = *(const short8*)(Qp + (size_t)(qr0 + 16 + ln) * 64 + quad * 8);
        const short8 qB1 = *(const short8*)(Qp + (size_t)(qr0 + 16 + ln) * 64 + quad * 8 + 32);

        float lsumA = 0.f, lsumB = 0.f;
        float4v oA[4], oB[4];
#pragma unroll
        for (int i = 0; i < 4; ++i) {
            oA[i] = (float4v){0.f, 0.f, 0.f, 0.f};
            oB[i] = (float4v){0.f, 0.f, 0.f, 0.f};
        }

        const int ktend = j >> 1;               // = (32j+31)>>6
        short8 kfA[8], kfB[8], vf[8];

        int kt = w;
        if (kt <= ktend) {
            LOADK(kfA, kt)
            while (true) {
                {
                    const bool more = (kt + 8) <= ktend;
                    LOADV(vf, kt)
                    if (more) LOADK(kfB, kt + 8)
                    STEP(kt, kfA, vf, kt == ktend)
                    kt += 8;
                    if (!more) break;
                }
                {
                    const bool more = (kt + 8) <= ktend;
                    LOADV(vf, kt)
                    if (more) LOADK(kfA, kt + 8)
                    STEP(kt, kfB, vf, kt == ktend)
                    kt += 8;
                    if (!more) break;
                }
            }
        }

        // deferred l reduction over quad (2 shfls per group)
        lsumA += __shfl_xor(lsumA, 16, 64);
        lsumA += __shfl_xor(lsumA, 32, 64);
        lsumB += __shfl_xor(lsumB, 16, 64);
        lsumB += __shfl_xor(lsumB, 32, 64);

        __syncthreads();   // all waves done with PLs before OL overwrites it

        // partials -> LDS (plain sum merge; no rescale needed)
#pragma unroll
        for (int vn = 0; vn < 4; ++vn)
#pragma unroll
            for (int r = 0; r < 4; ++r) {
                OLf[((size_t)w * 32 + quad * 4 + r) * 68 + vn * 16 + ln]      = oA[vn][r];
                OLf[((size_t)w * 32 + 16 + quad * 4 + r) * 68 + vn * 16 + ln] = oB[vn][r];
            }
        if (quad == 0) {
            SLf[w * 32 + ln]      = lsumA;
            SLf[w * 32 + 16 + ln] = lsumB;
        }
        __syncthreads();

        // merge: (w,quad) owns one of 32 rows; sum 8 split-K partials
        const int row = w * 4 + quad;
        float lstar = 0.f;
#pragma unroll
        for (int p = 0; p < 8; ++p) lstar += SLf[p * 32 + row];
        float ox = 0.f, oy = 0.f, oz = 0.f, ow_ = 0.f;
#pragma unroll
        for (int p = 0; p < 8; ++p) {
            const float4 ov = *(const float4*)&OLf[((size_t)p * 32 + row) * 68 + ln * 4];
            ox += ov.x; oy += ov.y; oz += ov.z; ow_ += ov.w;
        }
        const float inv = 1.f / lstar;
        float4 res; res.x = ox * inv; res.y = oy * inv; res.z = oz * inv; res.w = ow_ * inv;
        *(float4*)(out + ((size_t)b * T_ + qr0 + row) * 64 + ln * 4) = res;
        __syncthreads();   // LDS reused by next job
    }
}

extern "C" void kernel_launch(void* const* d_in, const int* in_sizes, int n_in,
                              void* d_out, int out_size, void* d_ws, size_t ws_size,
                              hipStream_t stream)
{
    const float* x    = (const float*)d_in[0];
    const float* cosp = (const float*)d_in[1];
    const float* sinp = (const float*)d_in[2];
    // d_in[3] = tril: unused (causality structural)
    const float* Wq   = (const float*)d_in[4];
    const float* Wk   = (const float*)d_in[5];
    const float* Wv   = (const float*)d_in[6];
    float* out = (float*)d_out;

    short* Qb  = (short*)d_ws;                // 16384*64 bf16 (pre-scaled)
    short* Ks  = Qb + (size_t)NROWS * 64;     // A-frag-major K
    short* Vs  = Ks + (size_t)NROWS * 64;     // B-frag-major V
    short* Wt2 = Vs + (size_t)NROWS * 64;     // 32*12*64*8 bf16 (frag-major)

    wprep_kernel<<<32, 256, 0, stream>>>(Wq, Wk, Wv, Wt2);
    qkv_kernel<<<NROWS / 32, 256, 0, stream>>>(x, cosp, sinp, Wt2, Qb, Ks, Vs);
    attn_kernel<<<256, 512, 0, stream>>>(Qb, Ks, Vs, out);
}

// Round 7
// 173.628 us; speedup vs baseline: 1.0820x; 1.0108x over previous
//
#include <hip/hip_runtime.h>
#include <math.h>

#define T_ 4096
#define NROWS 16384            // B*T

typedef __attribute__((ext_vector_type(8))) short short8;   // 8 bf16
typedef __attribute__((ext_vector_type(4))) short short4v;  // 4 bf16
typedef __attribute__((ext_vector_type(4))) float float4v;
typedef __attribute__((ext_vector_type(2))) unsigned uint2v;

#define MFMA(a, b, c) __builtin_amdgcn_mfma_f32_16x16x32_bf16((a), (b), (c), 0, 0, 0)

#if defined(__has_builtin)
#if __has_builtin(__builtin_amdgcn_exp2f)
#define EXP2(x) __builtin_amdgcn_exp2f(x)
#else
#define EXP2(x) exp2f(x)
#endif
#else
#define EXP2(x) exp2f(x)
#endif

#define SCALE_Q 0.18033688011112042f   // 0.125 * log2(e), folded into Q

__device__ __forceinline__ short f2bf(float f) {
    unsigned u = __builtin_bit_cast(unsigned, f);
    u += 0x7fffu + ((u >> 16) & 1u);          // RNE truncate to bf16
    return (short)(u >> 16);
}
__device__ __forceinline__ float bf2f(short s) {
    return __builtin_bit_cast(float, ((unsigned)(unsigned short)s) << 16);
}
__device__ __forceinline__ unsigned pack_bf2(float a, float b) {
    unsigned ua = __builtin_bit_cast(unsigned, a);
    unsigned ub = __builtin_bit_cast(unsigned, b);
    ua += 0x7fffu + ((ua >> 16) & 1u);
    ub += 0x7fffu + ((ub >> 16) & 1u);
    return (ua >> 16) | (ub & 0xffff0000u);
}

// ---------------------------------------------------------------------------
// Kernel 0: weights fp32 (C x 64) -> Wt2 in FRAGMENT-MAJOR layout.
// ---------------------------------------------------------------------------
__global__ void wprep_kernel(const float* __restrict__ Wq,
                             const float* __restrict__ Wk,
                             const float* __restrict__ Wv,
                             short* __restrict__ Wt2)
{
    const int ck = blockIdx.x;            // 0..31 (k chunk of 32)
    const int t = threadIdx.x;
    const int sub = t >> 6, lane = t & 63;
    const int ln = lane & 15, quad = lane >> 4;
#pragma unroll
    for (int jj = 0; jj < 3; ++jj) {
        const int nt = sub * 3 + jj;      // 0..11
        const float* W = (nt < 4) ? Wq : (nt < 8) ? Wk : Wv;
        const int col = (nt & 3) * 16 + ln;
        short8 o;
#pragma unroll
        for (int j = 0; j < 8; ++j)
            o[j] = f2bf(W[(size_t)(ck * 32 + quad * 8 + j) * 64 + col]);
        *(short8*)(Wt2 + ((size_t)(ck * 12 + nt) * 64 + lane) * 8) = o;
    }
}

// ---------------------------------------------------------------------------
// Kernel 1: MFMA QKV projection + fused RoPE, 4-way split-K, 32 rows/block.
// (unchanged this round)
// ---------------------------------------------------------------------------
__global__ __launch_bounds__(256, 2) void qkv_kernel(
    const float* __restrict__ x, const float* __restrict__ cosp,
    const float* __restrict__ sinp, const short* __restrict__ Wt2,
    short* __restrict__ Qb, short* __restrict__ Ks, short* __restrict__ Vs)
{
    __shared__ short4v MB[4][2][12][64];    // bf16 partial acc, 48 KB
    __shared__ short KT[32][72];            // K transpose tile (+pad), 4.5 KB

    const int t = threadIdx.x, w = t >> 6, lane = t & 63;
    const int ln = lane & 15, quad = lane >> 4;
    const int rb = blockIdx.x * 32;
    const int k0 = w * 256;

    const float* xp0 = x + (size_t)(rb + ln) * 1024 + k0 + quad * 8;
    const float* xp1 = x + (size_t)(rb + 16 + ln) * 1024 + k0 + quad * 8;
    const short* wp2 = Wt2 + ((size_t)(w * 8) * 12 * 64 + lane) * 8;

    // ---- Phase A: preload + convert all x for this wave ----
    short8 a[2][8];
#pragma unroll
    for (int af = 0; af < 2; ++af) {
        const float* xp = af ? xp1 : xp0;
        float4 xf[16];
#pragma unroll
        for (int it = 0; it < 8; ++it) {
            xf[it * 2]     = *(const float4*)(xp + it * 32);
            xf[it * 2 + 1] = *(const float4*)(xp + it * 32 + 4);
        }
#pragma unroll
        for (int it = 0; it < 8; ++it) {
            short8 v;
            v[0] = f2bf(xf[it * 2].x);     v[1] = f2bf(xf[it * 2].y);
            v[2] = f2bf(xf[it * 2].z);     v[3] = f2bf(xf[it * 2].w);
            v[4] = f2bf(xf[it * 2 + 1].x); v[5] = f2bf(xf[it * 2 + 1].y);
            v[6] = f2bf(xf[it * 2 + 1].z); v[7] = f2bf(xf[it * 2 + 1].w);
            a[af][it] = v;
        }
    }

    float4v acc[2][12];
#pragma unroll
    for (int af = 0; af < 2; ++af)
#pragma unroll
        for (int i = 0; i < 12; ++i) acc[af][i] = (float4v){0.f, 0.f, 0.f, 0.f};

    // ---- Phase B: W (frag-major, coalesced) -> MFMA ----
#pragma unroll
    for (int it = 0; it < 8; ++it) {
        short8 bf[12];
#pragma unroll
        for (int nt = 0; nt < 12; ++nt)
            bf[nt] = *(const short8*)(wp2 + (size_t)(it * 12 + nt) * 512);
#pragma unroll
        for (int nt = 0; nt < 12; ++nt) {
            acc[0][nt] = MFMA(a[0][it], bf[nt], acc[0][nt]);
            acc[1][nt] = MFMA(a[1][it], bf[nt], acc[1][nt]);
        }
    }

    // partials -> LDS (bf16)
#pragma unroll
    for (int af = 0; af < 2; ++af)
#pragma unroll
        for (int nt = 0; nt < 12; ++nt) {
            short4v pv;
#pragma unroll
            for (int reg = 0; reg < 4; ++reg) pv[reg] = f2bf(acc[af][nt][reg]);
            MB[w][af][nt][lane] = pv;
        }
    __syncthreads();

    // merge + epilogue: wave w handles nt = 3w..3w+2, both row groups
    const int b  = rb >> 12;
    const int kt = (rb & (T_ - 1)) >> 6;
#pragma unroll
    for (int af = 0; af < 2; ++af) {
        const int rb16 = rb + af * 16;
#pragma unroll
        for (int j = 0; j < 3; ++j) {
            const int nt = w * 3 + j;
            float m[4] = {0.f, 0.f, 0.f, 0.f};
#pragma unroll
            for (int p = 0; p < 4; ++p) {
                const short4v pv = MB[p][af][nt][lane];
#pragma unroll
                for (int reg = 0; reg < 4; ++reg) m[reg] += bf2f(pv[reg]);
            }
            if (nt < 4) {                          // Q + RoPE (scaled), row-major
                const int col = nt * 16 + ln;
#pragma unroll
                for (int reg = 0; reg < 4; ++reg) {
                    const int g  = rb16 + quad * 4 + reg;
                    const int tp = g & (T_ - 1);
                    const float cv = cosp[(size_t)tp * 64 + col];
                    const float sv = sinp[(size_t)tp * 64 + col];
                    const float v  = m[reg];
                    const float vp = __shfl_xor(v, 1, 64);
                    const float rot = (ln & 1) ? vp : -vp;
                    Qb[(size_t)g * 64 + col] = f2bf(fmaf(v, cv, rot * sv) * SCALE_Q);
                }
            } else if (nt < 8) {                   // K + RoPE -> LDS transpose tile
                const int col = (nt & 3) * 16 + ln;
#pragma unroll
                for (int reg = 0; reg < 4; ++reg) {
                    const int g  = rb16 + quad * 4 + reg;
                    const int tp = g & (T_ - 1);
                    const float cv = cosp[(size_t)tp * 64 + col];
                    const float sv = sinp[(size_t)tp * 64 + col];
                    const float v  = m[reg];
                    const float vp = __shfl_xor(v, 1, 64);
                    const float rot = (ln & 1) ? vp : -vp;
                    KT[af * 16 + quad * 4 + reg][col] = f2bf(fmaf(v, cv, rot * sv));
                }
            } else {                               // V -> swizzled B-frag layout
                const int vnt = nt - 8;
                const int rowgrp = (rb16 >> 4) & 3;
                const int hh = rowgrp >> 1;
                const int qp = (rowgrp & 1) * 2 + (quad >> 1);
                const int jb = (quad & 1) * 4;
                short4v pv;
#pragma unroll
                for (int reg = 0; reg < 4; ++reg) pv[reg] = f2bf(m[reg]);
                const size_t addr =
                    ((((size_t)(b * 64 + kt) * 4 + vnt) * 2 + hh) * 64 + qp * 16 + ln) * 8 + jb;
                *(short4v*)(Vs + addr) = pv;
            }
        }
    }
    __syncthreads();   // KT complete

    // K frag-major store: wave w handles (af2 = w>>1, h2 = w&1); coalesced 1 KB
    {
        const int af2 = w >> 1, h2 = w & 1;
        const int st2 = ((rb >> 4) & 3) + af2;     // 16-row group within 64-tile
        const short8 kfrag = *(const short8*)(&KT[af2 * 16 + ln][h2 * 32 + quad * 8]);
        *(short8*)(Ks + (((size_t)(b * 64 + kt) * 8 + st2 * 2 + h2) * 64 + lane) * 8) = kfrag;
    }
}

// ---------------------------------------------------------------------------
// Kernel 2: MFMA flash attention — ROUND 6: R4 structure (32-row Q-tile,
// 8-wave split-K, single-V / double-K buffers, ~200 VGPR no-spill) plus two
// chain-latency shavings:
//   * P pack via v_cvt_pk_bf16_f32 (1 instr/pair, RNE identical to pack_bf2's
//     bit math): removes ~150 VALU cy/STEP from the serial QK->exp->pack->
//     LDS->PV chain.
//   * s_setprio(1) around both MFMA clusters (T5): waves here are barrier-
//     free and phase-diverse, the regime where setprio measured +4-7% on attn.
// ---------------------------------------------------------------------------
#define LOADK(kf, ktv)                                                         \
    {   const short* _kb = Ksp + (size_t)(ktv) * 4096 + lane * 8;              \
        _Pragma("unroll")                                                      \
        for (int u = 0; u < 8; ++u) kf[u] = *(const short8*)(_kb + u * 512); }

#define LOADV(vf, ktv)                                                         \
    {   const short* _vb = Vp + (size_t)(ktv) * 4096 + lane * 8;               \
        _Pragma("unroll")                                                      \
        for (int u = 0; u < 8; ++u) vf[u] = *(const short8*)(_vb + u * 512); }

#define CVTPK(dst, lo, hi)                                                     \
    asm("v_cvt_pk_bf16_f32 %0, %1, %2" : "=v"(dst) : "v"(lo), "v"(hi));

#define STEP(ktv, kf, vf, masked)                                              \
    {   float4v sA[4], sB[4];                                                  \
        __builtin_amdgcn_s_setprio(1);                                         \
        _Pragma("unroll")                                                      \
        for (int st = 0; st < 4; ++st) {                                       \
            sA[st] = (float4v){0.f, 0.f, 0.f, 0.f};                            \
            sA[st] = MFMA(kf[st * 2],     qA0, sA[st]);  /* S^T = K*Q^T */     \
            sA[st] = MFMA(kf[st * 2 + 1], qA1, sA[st]);                        \
            sB[st] = (float4v){0.f, 0.f, 0.f, 0.f};                            \
            sB[st] = MFMA(kf[st * 2],     qB0, sB[st]);                        \
            sB[st] = MFMA(kf[st * 2 + 1], qB1, sB[st]);                        \
        }                                                                      \
        __builtin_amdgcn_s_setprio(0);                                         \
        if (masked) {                                                          \
            _Pragma("unroll")                                                  \
            for (int st = 0; st < 4; ++st)                                     \
                _Pragma("unroll")                                              \
                for (int r = 0; r < 4; ++r) {                                  \
                    const int kc = (ktv) * 64 + st * 16 + quad * 4 + r;        \
                    if (kc > qr0 + ln)      sA[st][r] = -__builtin_inff();     \
                    if (kc > qr0 + 16 + ln) sB[st][r] = -__builtin_inff();     \
                }                                                              \
        }                                                                      \
        _Pragma("unroll")                                                      \
        for (int st = 0; st < 4; ++st)                                         \
            _Pragma("unroll")                                                  \
            for (int r = 0; r < 4; ++r) {                                      \
                const float pA = EXP2(sA[st][r]);                              \
                sA[st][r] = pA; lsumA += pA;                                   \
                const float pB = EXP2(sB[st][r]);                              \
                sB[st][r] = pB; lsumB += pB;                                   \
            }                                                                  \
        _Pragma("unroll")                                                      \
        for (int st = 0; st < 4; ++st) {                                       \
            uint2v pkA, pkB;                                                   \
            CVTPK(pkA[0], sA[st][0], sA[st][1])                                \
            CVTPK(pkA[1], sA[st][2], sA[st][3])                                \
            *(uint2v*)(pwA + ln * 104 + st * 16 + quad * 4) = pkA;             \
            CVTPK(pkB[0], sB[st][0], sB[st][1])                                \
            CVTPK(pkB[1], sB[st][2], sB[st][3])                                \
            *(uint2v*)(pwB + ln * 104 + st * 16 + quad * 4) = pkB;             \
        }                                                                      \
        const short8 aA0 = *(const short8*)(pwA + ln * 104 + quad * 8);        \
        const short8 aA1 = *(const short8*)(pwA + ln * 104 + quad * 8 + 32);   \
        const short8 aB0 = *(const short8*)(pwB + ln * 104 + quad * 8);        \
        const short8 aB1 = *(const short8*)(pwB + ln * 104 + quad * 8 + 32);   \
        __builtin_amdgcn_s_setprio(1);                                         \
        _Pragma("unroll")                                                      \
        for (int vn = 0; vn < 4; ++vn) {                                       \
            oA[vn] = MFMA(aA0, vf[vn * 2],     oA[vn]);                        \
            oA[vn] = MFMA(aA1, vf[vn * 2 + 1], oA[vn]);                        \
            oB[vn] = MFMA(aB0, vf[vn * 2],     oB[vn]);                        \
            oB[vn] = MFMA(aB1, vf[vn * 2 + 1], oB[vn]);                        \
        }                                                                      \
        __builtin_amdgcn_s_setprio(0);                                         \
    }

__global__ __launch_bounds__(512, 2) void attn_kernel(
    const short* __restrict__ Qb, const short* __restrict__ Ks,
    const short* __restrict__ Vs, float* __restrict__ out)
{
    // Union-aliased shared memory:
    //   main loop : PLs = short[8 waves][2 groups][16*104]   (53,248 B)
    //   epilogue  : OLf = float[8][32][68] (69,632 B) ; SLf = float[8][32]
    __shared__ __align__(16) unsigned char smem[70656];
    short* const PLs = (short*)smem;
    float* const OLf = (float*)smem;
    float* const SLf = (float*)(smem + 69632);

    const int t = threadIdx.x, w = t >> 6, lane = t & 63;
    const int ln = lane & 15, quad = lane >> 4;
    const int bid = (int)blockIdx.x;
    const int b = bid >> 6;            // batch 0..3
    const int q = bid & 63;            // pair id 0..63

    const short* Qp  = Qb + (size_t)b * T_ * 64;
    const short* Ksp = Ks + (size_t)b * T_ * 64;
    const short* Vp  = Vs + (size_t)b * T_ * 64;
    short* const pwA = PLs + (size_t)(w * 2) * 1664;
    short* const pwB = pwA + 1664;

    for (int job = 0; job < 2; ++job) {
        const int j   = job ? 127 - q : q;      // complementary pair: 65-66 steps/block
        const int qr0 = j * 32;

        const short8 qA0 = *(const short8*)(Qp + (size_t)(qr0 + ln) * 64 + quad * 8);
        const short8 qA1 = *(const short8*)(Qp + (size_t)(qr0 + ln) * 64 + quad * 8 + 32);
        const short8 qB0 = *(const short8*)(Qp + (size_t)(qr0 + 16 + ln) * 64 + quad * 8);
        const short8 qB1 = *(const short8*)(Qp + (size_t)(qr0 + 16 + ln) * 64 + quad * 8 + 32);

        float lsumA = 0.f, lsumB = 0.f;
        float4v oA[4], oB[4];
#pragma unroll
        for (int i = 0; i < 4; ++i) {
            oA[i] = (float4v){0.f, 0.f, 0.f, 0.f};
            oB[i] = (float4v){0.f, 0.f, 0.f, 0.f};
        }

        const int ktend = j >> 1;               // = (32j+31)>>6
        short8 kfA[8], kfB[8], vf[8];

        int kt = w;
        if (kt <= ktend) {
            LOADK(kfA, kt)
            while (true) {
                {
                    const bool more = (kt + 8) <= ktend;
                    LOADV(vf, kt)
                    if (more) LOADK(kfB, kt + 8)
                    STEP(kt, kfA, vf, kt == ktend)
                    kt += 8;
                    if (!more) break;
                }
                {
                    const bool more = (kt + 8) <= ktend;
                    LOADV(vf, kt)
                    if (more) LOADK(kfA, kt + 8)
                    STEP(kt, kfB, vf, kt == ktend)
                    kt += 8;
                    if (!more) break;
                }
            }
        }

        // deferred l reduction over quad (2 shfls per group)
        lsumA += __shfl_xor(lsumA, 16, 64);
        lsumA += __shfl_xor(lsumA, 32, 64);
        lsumB += __shfl_xor(lsumB, 16, 64);
        lsumB += __shfl_xor(lsumB, 32, 64);

        __syncthreads();   // all waves done with PLs before OL overwrites it

        // partials -> LDS (plain sum merge; no rescale needed)
#pragma unroll
        for (int vn = 0; vn < 4; ++vn)
#pragma unroll
            for (int r = 0; r < 4; ++r) {
                OLf[((size_t)w * 32 + quad * 4 + r) * 68 + vn * 16 + ln]      = oA[vn][r];
                OLf[((size_t)w * 32 + 16 + quad * 4 + r) * 68 + vn * 16 + ln] = oB[vn][r];
            }
        if (quad == 0) {
            SLf[w * 32 + ln]      = lsumA;
            SLf[w * 32 + 16 + ln] = lsumB;
        }
        __syncthreads();

        // merge: (w,quad) owns one of 32 rows; sum 8 split-K partials
        const int row = w * 4 + quad;
        float lstar = 0.f;
#pragma unroll
        for (int p = 0; p < 8; ++p) lstar += SLf[p * 32 + row];
        float ox = 0.f, oy = 0.f, oz = 0.f, ow_ = 0.f;
#pragma unroll
        for (int p = 0; p < 8; ++p) {
            const float4 ov = *(const float4*)&OLf[((size_t)p * 32 + row) * 68 + ln * 4];
            ox += ov.x; oy += ov.y; oz += ov.z; ow_ += ov.w;
        }
        const float inv = 1.f / lstar;
        float4 res; res.x = ox * inv; res.y = oy * inv; res.z = oz * inv; res.w = ow_ * inv;
        *(float4*)(out + ((size_t)b * T_ + qr0 + row) * 64 + ln * 4) = res;
        __syncthreads();   // LDS reused by next job
    }
}

extern "C" void kernel_launch(void* const* d_in, const int* in_sizes, int n_in,
                              void* d_out, int out_size, void* d_ws, size_t ws_size,
                              hipStream_t stream)
{
    const float* x    = (const float*)d_in[0];
    const float* cosp = (const float*)d_in[1];
    const float* sinp = (const float*)d_in[2];
    // d_in[3] = tril: unused (causality structural)
    const float* Wq   = (const float*)d_in[4];
    const float* Wk   = (const float*)d_in[5];
    const float* Wv   = (const float*)d_in[6];
    float* out = (float*)d_out;

    short* Qb  = (short*)d_ws;                // 16384*64 bf16 (pre-scaled)
    short* Ks  = Qb + (size_t)NROWS * 64;     // A-frag-major K
    short* Vs  = Ks + (size_t)NROWS * 64;     // B-frag-major V
    short* Wt2 = Vs + (size_t)NROWS * 64;     // 32*12*64*8 bf16 (frag-major)

    wprep_kernel<<<32, 256, 0, stream>>>(Wq, Wk, Wv, Wt2);
    qkv_kernel<<<NROWS / 32, 256, 0, stream>>>(x, cosp, sinp, Wt2, Qb, Ks, Vs);
    attn_kernel<<<256, 512, 0, stream>>>(Qb, Ks, Vs, out);
}

// Round 8
// 171.775 us; speedup vs baseline: 1.0936x; 1.0108x over previous
//
#include <hip/hip_runtime.h>
#include <math.h>

#define T_ 4096
#define NROWS 16384            // B*T

typedef __attribute__((ext_vector_type(8))) short short8;   // 8 bf16
typedef __attribute__((ext_vector_type(4))) short short4v;  // 4 bf16
typedef __attribute__((ext_vector_type(4))) float float4v;
typedef __attribute__((ext_vector_type(2))) unsigned uint2v;

#define MFMA(a, b, c) __builtin_amdgcn_mfma_f32_16x16x32_bf16((a), (b), (c), 0, 0, 0)

#if defined(__has_builtin)
#if __has_builtin(__builtin_amdgcn_exp2f)
#define EXP2(x) __builtin_amdgcn_exp2f(x)
#else
#define EXP2(x) exp2f(x)
#endif
#else
#define EXP2(x) exp2f(x)
#endif

#define SCALE_Q 0.18033688011112042f   // 0.125 * log2(e), folded into Q

__device__ __forceinline__ short f2bf(float f) {
    unsigned u = __builtin_bit_cast(unsigned, f);
    u += 0x7fffu + ((u >> 16) & 1u);          // RNE truncate to bf16
    return (short)(u >> 16);
}
__device__ __forceinline__ float bf2f(short s) {
    return __builtin_bit_cast(float, ((unsigned)(unsigned short)s) << 16);
}

// ---------------------------------------------------------------------------
// Kernel 0: weights fp32 (C x 64) -> Wt2 in FRAGMENT-MAJOR layout.
// ---------------------------------------------------------------------------
__global__ void wprep_kernel(const float* __restrict__ Wq,
                             const float* __restrict__ Wk,
                             const float* __restrict__ Wv,
                             short* __restrict__ Wt2)
{
    const int ck = blockIdx.x;            // 0..31 (k chunk of 32)
    const int t = threadIdx.x;
    const int sub = t >> 6, lane = t & 63;
    const int ln = lane & 15, quad = lane >> 4;
#pragma unroll
    for (int jj = 0; jj < 3; ++jj) {
        const int nt = sub * 3 + jj;      // 0..11
        const float* W = (nt < 4) ? Wq : (nt < 8) ? Wk : Wv;
        const int col = (nt & 3) * 16 + ln;
        short8 o;
#pragma unroll
        for (int j = 0; j < 8; ++j)
            o[j] = f2bf(W[(size_t)(ck * 32 + quad * 8 + j) * 64 + col]);
        *(short8*)(Wt2 + ((size_t)(ck * 12 + nt) * 64 + lane) * 8) = o;
    }
}

// ---------------------------------------------------------------------------
// Kernel 1: MFMA QKV projection + fused RoPE, 4-way split-K, 32 rows/block.
// (unchanged this round)
// ---------------------------------------------------------------------------
__global__ __launch_bounds__(256, 2) void qkv_kernel(
    const float* __restrict__ x, const float* __restrict__ cosp,
    const float* __restrict__ sinp, const short* __restrict__ Wt2,
    short* __restrict__ Qb, short* __restrict__ Ks, short* __restrict__ Vs)
{
    __shared__ short4v MB[4][2][12][64];    // bf16 partial acc, 48 KB
    __shared__ short KT[32][72];            // K transpose tile (+pad), 4.5 KB

    const int t = threadIdx.x, w = t >> 6, lane = t & 63;
    const int ln = lane & 15, quad = lane >> 4;
    const int rb = blockIdx.x * 32;
    const int k0 = w * 256;

    const float* xp0 = x + (size_t)(rb + ln) * 1024 + k0 + quad * 8;
    const float* xp1 = x + (size_t)(rb + 16 + ln) * 1024 + k0 + quad * 8;
    const short* wp2 = Wt2 + ((size_t)(w * 8) * 12 * 64 + lane) * 8;

    // ---- Phase A: preload + convert all x for this wave ----
    short8 a[2][8];
#pragma unroll
    for (int af = 0; af < 2; ++af) {
        const float* xp = af ? xp1 : xp0;
        float4 xf[16];
#pragma unroll
        for (int it = 0; it < 8; ++it) {
            xf[it * 2]     = *(const float4*)(xp + it * 32);
            xf[it * 2 + 1] = *(const float4*)(xp + it * 32 + 4);
        }
#pragma unroll
        for (int it = 0; it < 8; ++it) {
            short8 v;
            v[0] = f2bf(xf[it * 2].x);     v[1] = f2bf(xf[it * 2].y);
            v[2] = f2bf(xf[it * 2].z);     v[3] = f2bf(xf[it * 2].w);
            v[4] = f2bf(xf[it * 2 + 1].x); v[5] = f2bf(xf[it * 2 + 1].y);
            v[6] = f2bf(xf[it * 2 + 1].z); v[7] = f2bf(xf[it * 2 + 1].w);
            a[af][it] = v;
        }
    }

    float4v acc[2][12];
#pragma unroll
    for (int af = 0; af < 2; ++af)
#pragma unroll
        for (int i = 0; i < 12; ++i) acc[af][i] = (float4v){0.f, 0.f, 0.f, 0.f};

    // ---- Phase B: W (frag-major, coalesced) -> MFMA ----
#pragma unroll
    for (int it = 0; it < 8; ++it) {
        short8 bf[12];
#pragma unroll
        for (int nt = 0; nt < 12; ++nt)
            bf[nt] = *(const short8*)(wp2 + (size_t)(it * 12 + nt) * 512);
#pragma unroll
        for (int nt = 0; nt < 12; ++nt) {
            acc[0][nt] = MFMA(a[0][it], bf[nt], acc[0][nt]);
            acc[1][nt] = MFMA(a[1][it], bf[nt], acc[1][nt]);
        }
    }

    // partials -> LDS (bf16)
#pragma unroll
    for (int af = 0; af < 2; ++af)
#pragma unroll
        for (int nt = 0; nt < 12; ++nt) {
            short4v pv;
#pragma unroll
            for (int reg = 0; reg < 4; ++reg) pv[reg] = f2bf(acc[af][nt][reg]);
            MB[w][af][nt][lane] = pv;
        }
    __syncthreads();

    // merge + epilogue: wave w handles nt = 3w..3w+2, both row groups
    const int b  = rb >> 12;
    const int kt = (rb & (T_ - 1)) >> 6;
#pragma unroll
    for (int af = 0; af < 2; ++af) {
        const int rb16 = rb + af * 16;
#pragma unroll
        for (int j = 0; j < 3; ++j) {
            const int nt = w * 3 + j;
            float m[4] = {0.f, 0.f, 0.f, 0.f};
#pragma unroll
            for (int p = 0; p < 4; ++p) {
                const short4v pv = MB[p][af][nt][lane];
#pragma unroll
                for (int reg = 0; reg < 4; ++reg) m[reg] += bf2f(pv[reg]);
            }
            if (nt < 4) {                          // Q + RoPE (scaled), row-major
                const int col = nt * 16 + ln;
#pragma unroll
                for (int reg = 0; reg < 4; ++reg) {
                    const int g  = rb16 + quad * 4 + reg;
                    const int tp = g & (T_ - 1);
                    const float cv = cosp[(size_t)tp * 64 + col];
                    const float sv = sinp[(size_t)tp * 64 + col];
                    const float v  = m[reg];
                    const float vp = __shfl_xor(v, 1, 64);
                    const float rot = (ln & 1) ? vp : -vp;
                    Qb[(size_t)g * 64 + col] = f2bf(fmaf(v, cv, rot * sv) * SCALE_Q);
                }
            } else if (nt < 8) {                   // K + RoPE -> LDS transpose tile
                const int col = (nt & 3) * 16 + ln;
#pragma unroll
                for (int reg = 0; reg < 4; ++reg) {
                    const int g  = rb16 + quad * 4 + reg;
                    const int tp = g & (T_ - 1);
                    const float cv = cosp[(size_t)tp * 64 + col];
                    const float sv = sinp[(size_t)tp * 64 + col];
                    const float v  = m[reg];
                    const float vp = __shfl_xor(v, 1, 64);
                    const float rot = (ln & 1) ? vp : -vp;
                    KT[af * 16 + quad * 4 + reg][col] = f2bf(fmaf(v, cv, rot * sv));
                }
            } else {                               // V -> swizzled B-frag layout
                const int vnt = nt - 8;
                const int rowgrp = (rb16 >> 4) & 3;
                const int hh = rowgrp >> 1;
                const int qp = (rowgrp & 1) * 2 + (quad >> 1);
                const int jb = (quad & 1) * 4;
                short4v pv;
#pragma unroll
                for (int reg = 0; reg < 4; ++reg) pv[reg] = f2bf(m[reg]);
                const size_t addr =
                    ((((size_t)(b * 64 + kt) * 4 + vnt) * 2 + hh) * 64 + qp * 16 + ln) * 8 + jb;
                *(short4v*)(Vs + addr) = pv;
            }
        }
    }
    __syncthreads();   // KT complete

    // K frag-major store: wave w handles (af2 = w>>1, h2 = w&1); coalesced 1 KB
    {
        const int af2 = w >> 1, h2 = w & 1;
        const int st2 = ((rb >> 4) & 3) + af2;     // 16-row group within 64-tile
        const short8 kfrag = *(const short8*)(&KT[af2 * 16 + ln][h2 * 32 + quad * 8]);
        *(short8*)(Ks + (((size_t)(b * 64 + kt) * 8 + st2 * 2 + h2) * 64 + lane) * 8) = kfrag;
    }
}

// ---------------------------------------------------------------------------
// Kernel 2: MFMA flash attention — ROUND 7: deferred-PV software pipeline
// (T15). PV of tile i runs at the START of step i+1: its P operand (LDS,
// double-buffered) and V (2 reg buffers) are ready, so PV issues immediately
// and hides the cold K-load latency of tile i+1; the P write->read LDS
// turnaround leaves the critical path entirely. K/V register budget is
// unchanged vs R6 (1 K buf + 2 V bufs = 96 VGPR — the R2 spill lesson).
// P LDS double-buffer: 8 waves x [p0A|p0B|p1A|p1B] x 1664 shorts = 104 KB,
// union-aliased with the epilogue OL/SL (barrier-separated, per-wave P is
// private so in-loop use is race-free).
// ---------------------------------------------------------------------------
#define LOADK(kf, ktv)                                                         \
    {   const short* _kb = Ksp + (size_t)(ktv) * 4096 + lane * 8;              \
        _Pragma("unroll")                                                      \
        for (int u = 0; u < 8; ++u) kf[u] = *(const short8*)(_kb + u * 512); }

#define LOADV(vf, ktv)                                                         \
    {   const short* _vb = Vp + (size_t)(ktv) * 4096 + lane * 8;               \
        _Pragma("unroll")                                                      \
        for (int u = 0; u < 8; ++u) vf[u] = *(const short8*)(_vb + u * 512); }

#define CVTPK(dst, lo, hi)                                                     \
    asm("v_cvt_pk_bf16_f32 %0, %1, %2" : "=v"(dst) : "v"(lo), "v"(hi));

// QK^T + softmax + pack + store P to LDS (pa/pb = this step's P buffers)
#define QKSOFT(ktv, pa, pb, masked)                                            \
    {   float4v sA[4], sB[4];                                                  \
        __builtin_amdgcn_s_setprio(1);                                         \
        _Pragma("unroll")                                                      \
        for (int st = 0; st < 4; ++st) {                                       \
            sA[st] = (float4v){0.f, 0.f, 0.f, 0.f};                            \
            sA[st] = MFMA(kf[st * 2],     qA0, sA[st]);  /* S^T = K*Q^T */     \
            sA[st] = MFMA(kf[st * 2 + 1], qA1, sA[st]);                        \
            sB[st] = (float4v){0.f, 0.f, 0.f, 0.f};                            \
            sB[st] = MFMA(kf[st * 2],     qB0, sB[st]);                        \
            sB[st] = MFMA(kf[st * 2 + 1], qB1, sB[st]);                        \
        }                                                                      \
        __builtin_amdgcn_s_setprio(0);                                         \
        if (masked) {                                                          \
            _Pragma("unroll")                                                  \
            for (int st = 0; st < 4; ++st)                                     \
                _Pragma("unroll")                                              \
                for (int r = 0; r < 4; ++r) {                                  \
                    const int kc = (ktv) * 64 + st * 16 + quad * 4 + r;        \
                    if (kc > qr0 + ln)      sA[st][r] = -__builtin_inff();     \
                    if (kc > qr0 + 16 + ln) sB[st][r] = -__builtin_inff();     \
                }                                                              \
        }                                                                      \
        _Pragma("unroll")                                                      \
        for (int st = 0; st < 4; ++st)                                         \
            _Pragma("unroll")                                                  \
            for (int r = 0; r < 4; ++r) {                                      \
                const float pA = EXP2(sA[st][r]);                              \
                sA[st][r] = pA; lsumA += pA;                                   \
                const float pB = EXP2(sB[st][r]);                              \
                sB[st][r] = pB; lsumB += pB;                                   \
            }                                                                  \
        _Pragma("unroll")                                                      \
        for (int st = 0; st < 4; ++st) {                                       \
            uint2v pkA, pkB;                                                   \
            CVTPK(pkA[0], sA[st][0], sA[st][1])                                \
            CVTPK(pkA[1], sA[st][2], sA[st][3])                                \
            *(uint2v*)((pa) + ln * 104 + st * 16 + quad * 4) = pkA;            \
            CVTPK(pkB[0], sB[st][0], sB[st][1])                                \
            CVTPK(pkB[1], sB[st][2], sB[st][3])                                \
            *(uint2v*)((pb) + ln * 104 + st * 16 + quad * 4) = pkB;            \
        }                                                                      \
    }

// PV for the PREVIOUS step: P from LDS (pa/pb), V from register buffer vv
#define PVSTEP(pa, pb, vv)                                                     \
    {   const short8 aA0 = *(const short8*)((pa) + ln * 104 + quad * 8);       \
        const short8 aA1 = *(const short8*)((pa) + ln * 104 + quad * 8 + 32);  \
        const short8 aB0 = *(const short8*)((pb) + ln * 104 + quad * 8);       \
        const short8 aB1 = *(const short8*)((pb) + ln * 104 + quad * 8 + 32);  \
        __builtin_amdgcn_s_setprio(1);                                         \
        _Pragma("unroll")                                                      \
        for (int vn = 0; vn < 4; ++vn) {                                       \
            oA[vn] = MFMA(aA0, vv[vn * 2],     oA[vn]);                        \
            oA[vn] = MFMA(aA1, vv[vn * 2 + 1], oA[vn]);                        \
            oB[vn] = MFMA(aB0, vv[vn * 2],     oB[vn]);                        \
            oB[vn] = MFMA(aB1, vv[vn * 2 + 1], oB[vn]);                        \
        }                                                                      \
        __builtin_amdgcn_s_setprio(0);                                         \
    }

__global__ __launch_bounds__(512, 2) void attn_kernel(
    const short* __restrict__ Qb, const short* __restrict__ Ks,
    const short* __restrict__ Vs, float* __restrict__ out)
{
    // Union-aliased shared memory:
    //   main loop : P dbuf = short[8 waves][4][1664]          (106,496 B)
    //   epilogue  : OLf = float[8][32][68] (69,632 B) ; SLf = float[8][32]
    __shared__ __align__(16) unsigned char smem[106496];
    short* const PLs = (short*)smem;
    float* const OLf = (float*)smem;
    float* const SLf = (float*)(smem + 69632);

    const int t = threadIdx.x, w = t >> 6, lane = t & 63;
    const int ln = lane & 15, quad = lane >> 4;
    const int bid = (int)blockIdx.x;
    const int b = bid >> 6;            // batch 0..3
    const int q = bid & 63;            // pair id 0..63

    const short* Qp  = Qb + (size_t)b * T_ * 64;
    const short* Ksp = Ks + (size_t)b * T_ * 64;
    const short* Vp  = Vs + (size_t)b * T_ * 64;
    short* const pw  = PLs + (size_t)w * 6656;    // [p0A|p0B|p1A|p1B]
    short* const p0A = pw;
    short* const p0B = pw + 1664;
    short* const p1A = pw + 3328;
    short* const p1B = pw + 4992;

    for (int job = 0; job < 2; ++job) {
        const int j   = job ? 127 - q : q;      // complementary pair: 65 steps/block
        const int qr0 = j * 32;

        const short8 qA0 = *(const short8*)(Qp + (size_t)(qr0 + ln) * 64 + quad * 8);
        const short8 qA1 = *(const short8*)(Qp + (size_t)(qr0 + ln) * 64 + quad * 8 + 32);
        const short8 qB0 = *(const short8*)(Qp + (size_t)(qr0 + 16 + ln) * 64 + quad * 8);
        const short8 qB1 = *(const short8*)(Qp + (size_t)(qr0 + 16 + ln) * 64 + quad * 8 + 32);

        float lsumA = 0.f, lsumB = 0.f;
        float4v oA[4], oB[4];
#pragma unroll
        for (int i = 0; i < 4; ++i) {
            oA[i] = (float4v){0.f, 0.f, 0.f, 0.f};
            oB[i] = (float4v){0.f, 0.f, 0.f, 0.f};
        }

        const int ktend = j >> 1;               // = (32j+31)>>6
        short8 kf[8], vf0[8], vf1[8];

        int kt = w;
        if (kt <= ktend) {
            // prologue: step 0 (QK+softmax only; its PV is deferred)
            LOADK(kf, kt)
            LOADV(vf0, kt)
            QKSOFT(kt, p0A, p0B, kt == ktend)
            kt += 8;
            // steady state: 2-step unrolled parity pipeline
            while (true) {
                if (kt > ktend) { PVSTEP(p0A, p0B, vf0) break; }
                LOADK(kf, kt)
                LOADV(vf1, kt)
                PVSTEP(p0A, p0B, vf0)            // prev PV hides cur K latency
                QKSOFT(kt, p1A, p1B, kt == ktend)
                kt += 8;
                if (kt > ktend) { PVSTEP(p1A, p1B, vf1) break; }
                LOADK(kf, kt)
                LOADV(vf0, kt)
                PVSTEP(p1A, p1B, vf1)
                QKSOFT(kt, p0A, p0B, kt == ktend)
                kt += 8;
            }
        }

        // deferred l reduction over quad (2 shfls per group)
        lsumA += __shfl_xor(lsumA, 16, 64);
        lsumA += __shfl_xor(lsumA, 32, 64);
        lsumB += __shfl_xor(lsumB, 16, 64);
        lsumB += __shfl_xor(lsumB, 32, 64);

        __syncthreads();   // all waves done with P LDS before OL overwrites it

        // partials -> LDS (plain sum merge; no rescale needed)
#pragma unroll
        for (int vn = 0; vn < 4; ++vn)
#pragma unroll
            for (int r = 0; r < 4; ++r) {
                OLf[((size_t)w * 32 + quad * 4 + r) * 68 + vn * 16 + ln]      = oA[vn][r];
                OLf[((size_t)w * 32 + 16 + quad * 4 + r) * 68 + vn * 16 + ln] = oB[vn][r];
            }
        if (quad == 0) {
            SLf[w * 32 + ln]      = lsumA;
            SLf[w * 32 + 16 + ln] = lsumB;
        }
        __syncthreads();

        // merge: (w,quad) owns one of 32 rows; sum 8 split-K partials
        const int row = w * 4 + quad;
        float lstar = 0.f;
#pragma unroll
        for (int p = 0; p < 8; ++p) lstar += SLf[p * 32 + row];
        float ox = 0.f, oy = 0.f, oz = 0.f, ow_ = 0.f;
#pragma unroll
        for (int p = 0; p < 8; ++p) {
            const float4 ov = *(const float4*)&OLf[((size_t)p * 32 + row) * 68 + ln * 4];
            ox += ov.x; oy += ov.y; oz += ov.z; ow_ += ov.w;
        }
        const float inv = 1.f / lstar;
        float4 res; res.x = ox * inv; res.y = oy * inv; res.z = oz * inv; res.w = ow_ * inv;
        *(float4*)(out + ((size_t)b * T_ + qr0 + row) * 64 + ln * 4) = res;
        __syncthreads();   // LDS reused by next job
    }
}

extern "C" void kernel_launch(void* const* d_in, const int* in_sizes, int n_in,
                              void* d_out, int out_size, void* d_ws, size_t ws_size,
                              hipStream_t stream)
{
    const float* x    = (const float*)d_in[0];
    const float* cosp = (const float*)d_in[1];
    const float* sinp = (const float*)d_in[2];
    // d_in[3] = tril: unused (causality structural)
    const float* Wq   = (const float*)d_in[4];
    const float* Wk   = (const float*)d_in[5];
    const float* Wv   = (const float*)d_in[6];
    float* out = (float*)d_out;

    short* Qb  = (short*)d_ws;                // 16384*64 bf16 (pre-scaled)
    short* Ks  = Qb + (size_t)NROWS * 64;     // A-frag-major K
    short* Vs  = Ks + (size_t)NROWS * 64;     // B-frag-major V
    short* Wt2 = Vs + (size_t)NROWS * 64;     // 32*12*64*8 bf16 (frag-major)

    wprep_kernel<<<32, 256, 0, stream>>>(Wq, Wk, Wv, Wt2);
    qkv_kernel<<<NROWS / 32, 256, 0, stream>>>(x, cosp, sinp, Wt2, Qb, Ks, Vs);
    attn_kernel<<<256, 512, 0, stream>>>(Qb, Ks, Vs, out);
}